// Round 5
// baseline (199.283 us; speedup 1.0000x reference)
//
#include <hip/hip_runtime.h>
#include <hip/hip_bf16.h>
#include <cstdint>

// MultiHeadSelfAttention N=2,L=2048,E=1024,H=16,D=64.
// Round 5: attn reads K/V MFMA fragments DIRECTLY from global (L1-resident
// tiles, no LDS staging, no barriers, no conflicts); 64q/wave; split-K x2
// across the 2 waves of a block (O,l additive under no-max softmax), one
// LDS combine at the end. P handoff via wave-private stride-72 LDS.
// proj: coalesced LDS-staged x tile + swizzled frag reads.

#define NB 2
#define LSEQ 2048
#define EMB 1024
#define NHEADS 16
#define HD 64

// (1/sqrt(1024)) * log2(e): folded into Wq bf16 conversion; P = exp2(S+bias)
#define QSCALE 0.045084220027780106f
#define MASKBIAS -1e30f

using short8 = __attribute__((ext_vector_type(8))) short;
using short4v = __attribute__((ext_vector_type(4))) short;
using f32x4 = __attribute__((ext_vector_type(4))) float;

__device__ inline short bf16of(float f) {
  union { __hip_bfloat16 b; short s; } u;
  u.b = __float2bfloat16(f);
  return u.s;
}

__device__ inline short4v pack4bf(float a, float b, float c, float d) {
  union { __hip_bfloat162 v[2]; short4v s; } u;
  u.v[0] = __float22bfloat162_rn(make_float2(a, b));
  u.v[1] = __float22bfloat162_rn(make_float2(c, d));
  return u.s;
}

__device__ inline short8 pack8bf(float4 a, float4 b) {
  union { short4v q[2]; short8 o; } u;
  u.q[0] = pack4bf(a.x, a.y, a.z, a.w);
  u.q[1] = pack4bf(b.x, b.y, b.z, b.w);
  return u.o;
}

__device__ inline float fexp2(float x) {
#if __has_builtin(__builtin_amdgcn_exp2f)
  return __builtin_amdgcn_exp2f(x);
#else
  return exp2f(x);
#endif
}

#define MFMA(A, B, C) __builtin_amdgcn_mfma_f32_16x16x32_bf16((A), (B), (C), 0, 0, 0)

// ---------------------------------------------------------------------------
// Convert Wo->bf16 (grid-wide), Wq(*QSCALE)/Wk/Wv->bf16 (blocks 0-2),
// mask->bias float (blocks 4-7).
__global__ __launch_bounds__(256) void conv_kernel(
    const float* __restrict__ Wq, const float* __restrict__ Wk,
    const float* __restrict__ Wv, const float* __restrict__ Wo,
    const int* __restrict__ mask, short* __restrict__ Wqb,
    short* __restrict__ Wkb, short* __restrict__ Wvb,
    short* __restrict__ Wob, float* __restrict__ biasf) {
  const int b = blockIdx.x, t = threadIdx.x;
  {
    int i = (b * 256 + t) * 4;  // 1024 blocks * 1024 = 1Mi elements of Wo
    float4 v = *(const float4*)&Wo[i];
    *(short4v*)&Wob[i] = pack4bf(v.x, v.y, v.z, v.w);
  }
  if (b < 3) {
    const float* src = (b == 0) ? Wq : (b == 1) ? Wk : Wv;
    short* dst = (b == 0) ? Wqb : (b == 1) ? Wkb : Wvb;
    const float sc = (b == 0) ? QSCALE : 1.0f;
#pragma unroll
    for (int i = 0; i < 4; ++i) {
      int j = t * 16 + i * 4;  // 256*16 = 4096
      float4 v = *(const float4*)&src[j];
      *(short4v*)&dst[j] = pack4bf(v.x * sc, v.y * sc, v.z * sc, v.w * sc);
    }
  } else if (b >= 4 && b < 8) {
    int i = ((b - 4) * 256 + t) * 4;  // 4096 mask ints
    int4 m = *(const int4*)&mask[i];
    float4 o;
    o.x = m.x ? 0.f : MASKBIAS;
    o.y = m.y ? 0.f : MASKBIAS;
    o.z = m.z ? 0.f : MASKBIAS;
    o.w = m.w ? 0.f : MASKBIAS;
    *(float4*)&biasf[i] = o;
  }
}

// ---------------------------------------------------------------------------
// Projections with coalesced LDS-staged x tile (bf16, XOR-swizzled).
// Block = (ltile 64, nh, z); 4 waves.
// z<2 (Q,K): C = W·x^T — wave wv owns l-cols wv*16..+15; A = W rows (global),
//   B = x rows from LDS. Out row-major [l][d].
// z==2 (V): C = x·W^T — wave wv owns d-cols wv*16..+15; A = x rows (LDS),
//   B = W rows (global). Out V^T [d][L].
__global__ __launch_bounds__(256) void proj_mfma(
    const float* __restrict__ xq, const float* __restrict__ xk,
    const float* __restrict__ xv, const short* __restrict__ Wqb,
    const short* __restrict__ Wkb, const short* __restrict__ Wvb,
    short* __restrict__ Qb, short* __restrict__ Kb, short* __restrict__ Vt) {
  __shared__ __align__(16) short xs[64 * 64];
  const int t = threadIdx.x;
  const int wv = t >> 6, lane = t & 63;
  const int quad = lane >> 4, l15 = lane & 15;
  const int z = blockIdx.z, nh = blockIdx.y;
  const int n = nh >> 4, h = nh & 15;
  const int l0 = blockIdx.x * 64;
  const float* x = (z == 0) ? xq : (z == 1) ? xk : xv;
  const short* W = (z == 0) ? Wqb : (z == 1) ? Wkb : Wvb;

  // Stage x tile: 512 16B-chunks; thread handles chunks t, t+256.
  // Per instruction: 8 rows x 256 B contiguous segments — fully coalesced.
#pragma unroll
  for (int i = 0; i < 2; ++i) {
    int cc = i * 256 + t, row = cc >> 3, ch = cc & 7;
    const float* g = x + ((size_t)n * LSEQ + l0 + row) * EMB + h * HD + ch * 8;
    float4 a = *(const float4*)g;
    float4 b = *(const float4*)(g + 4);
    *(short8*)&xs[row * 64 + ((ch ^ (row & 7)) * 8)] = pack8bf(a, b);
  }
  __syncthreads();

  f32x4 acc[4];
#pragma unroll
  for (int a = 0; a < 4; ++a) acc[a] = (f32x4){0.f, 0.f, 0.f, 0.f};

  if (z < 2) {
    short8 xf[2];
#pragma unroll
    for (int c = 0; c < 2; ++c)
      xf[c] = *(const short8*)&xs[(wv * 16 + l15) * 64 +
                                  (((c * 4 + quad) ^ (l15 & 7)) * 8)];
#pragma unroll
    for (int c = 0; c < 2; ++c)
#pragma unroll
      for (int mt = 0; mt < 4; ++mt) {
        short8 wf = *(const short8*)(W + (mt * 16 + l15) * HD + c * 32 + quad * 8);
        acc[mt] = MFMA(wf, xf[c], acc[mt]);
      }
    // lane: l = l0+wv*16+l15 (col), d = mt*16+quad*4+r (row)
    short* ob = ((z == 0) ? Qb : Kb) + ((size_t)nh * LSEQ + l0 + wv * 16 + l15) * HD;
#pragma unroll
    for (int mt = 0; mt < 4; ++mt)
      *(short4v*)&ob[mt * 16 + quad * 4] =
          pack4bf(acc[mt][0], acc[mt][1], acc[mt][2], acc[mt][3]);
  } else {
    short8 wf[2];
#pragma unroll
    for (int c = 0; c < 2; ++c)
      wf[c] = *(const short8*)(W + (wv * 16 + l15) * HD + c * 32 + quad * 8);
#pragma unroll
    for (int c = 0; c < 2; ++c)
#pragma unroll
      for (int mt = 0; mt < 4; ++mt) {
        short8 af = *(const short8*)&xs[(mt * 16 + l15) * 64 +
                                        (((c * 4 + quad) ^ (l15 & 7)) * 8)];
        acc[mt] = MFMA(af, wf[c], acc[mt]);
      }
    // lane: d = wv*16+l15 (col), l = l0+mt*16+quad*4+r (row) -> V^T store
    short* vb = Vt + ((size_t)nh * HD + wv * 16 + l15) * LSEQ + l0;
#pragma unroll
    for (int mt = 0; mt < 4; ++mt)
      *(short4v*)&vb[mt * 16 + quad * 4] =
          pack4bf(acc[mt][0], acc[mt][1], acc[mt][2], acc[mt][3]);
  }
}

// ---------------------------------------------------------------------------
// Flash attention, direct-global fragments, split-K.
// Block = 2 waves = 128 thr, both waves own the SAME 64 q; wave wv scans
// k-tiles [wv*16, wv*16+16). No barriers in the loop; P via wave-private
// LDS (stride 72). End: one-shot LDS combine (O,l additive).
// Grid (LSEQ/64, N*H) = (32, 32) = 1024 blocks -> 4 blocks/CU, 8 waves/CU.
__global__ __launch_bounds__(128, 2) void attn_kernel(
    const short* __restrict__ Qg,    // [nh][L][64] bf16 (Wq pre-scaled)
    const short* __restrict__ Kg,    // [nh][L][64] bf16
    const short* __restrict__ Vtg,   // [nh][64][L] bf16
    const float* __restrict__ biasf, // [N][L]: 0 or -1e30
    short* __restrict__ AO)          // [N*L][E] bf16
{
  __shared__ __align__(16) short Pw[2][64 * 72];  // 18.4 KB; aliased for combine

  const int t = threadIdx.x;
  const int wv = t >> 6, lane = t & 63;
  const int quad = lane >> 4, l15 = lane & 15;
  const int nh = blockIdx.y;
  const int n = nh >> 4, h = nh & 15;
  const int q0 = blockIdx.x * 64;

  const short* kbase = Kg + (size_t)nh * LSEQ * HD;
  const short* vbase = Vtg + (size_t)nh * HD * LSEQ;
  const float* bbase = biasf + n * LSEQ;

  // Resident Q B-fragments: B[d = c*32+quad*8+j][q = ntq*16+l15]
  short8 qf[4][2];
#pragma unroll
  for (int ntq = 0; ntq < 4; ++ntq)
#pragma unroll
    for (int c = 0; c < 2; ++c)
      qf[ntq][c] = *(const short8*)(Qg +
          ((size_t)nh * LSEQ + q0 + ntq * 16 + l15) * HD + c * 32 + quad * 8);

  f32x4 O[4][4], Ol[4];
#pragma unroll
  for (int a = 0; a < 4; ++a) {
    Ol[a] = (f32x4){0.f, 0.f, 0.f, 0.f};
#pragma unroll
    for (int b = 0; b < 4; ++b) O[a][b] = (f32x4){0.f, 0.f, 0.f, 0.f};
  }
  const short one_bf = (short)0x3F80;
  const short8 ones = {one_bf, one_bf, one_bf, one_bf,
                       one_bf, one_bf, one_bf, one_bf};

  const int ktB = wv * 16;
  for (int kk = 0; kk < 16; ++kk) {
    const int k0 = (ktB + kk) * 64;

    // ---- S^T = K·Q^T + bias; K A-frags straight from global (L1 gather)
    f32x4 St[4][4];
#pragma unroll
    for (int mt = 0; mt < 4; ++mt) {
      f32x4 bv = *(const f32x4*)(bbase + k0 + mt * 16 + quad * 4);
#pragma unroll
      for (int ntq = 0; ntq < 4; ++ntq) St[mt][ntq] = bv;
    }
#pragma unroll
    for (int c = 0; c < 2; ++c) {
      short8 kf[4];
#pragma unroll
      for (int mt = 0; mt < 4; ++mt)
        kf[mt] = *(const short8*)(kbase + (size_t)(k0 + mt * 16 + l15) * HD +
                                  c * 32 + quad * 8);
#pragma unroll
      for (int mt = 0; mt < 4; ++mt)
#pragma unroll
        for (int ntq = 0; ntq < 4; ++ntq)
          St[mt][ntq] = MFMA(kf[mt], qf[ntq][c], St[mt][ntq]);
    }

    // ---- P = exp2(St); pack -> wave-private Pl[q][k]
#pragma unroll
    for (int ntq = 0; ntq < 4; ++ntq)
#pragma unroll
      for (int mt = 0; mt < 4; ++mt) {
#pragma unroll
        for (int r = 0; r < 4; ++r) St[mt][ntq][r] = fexp2(St[mt][ntq][r]);
        *(short4v*)&Pw[wv][(ntq * 16 + l15) * 72 + mt * 16 + quad * 4] =
            pack4bf(St[mt][ntq][0], St[mt][ntq][1], St[mt][ntq][2],
                    St[mt][ntq][3]);
      }

    // ---- PV + l; V B-frags straight from global
#pragma unroll
    for (int c = 0; c < 2; ++c) {
      short8 pf[4];
#pragma unroll
      for (int mq = 0; mq < 4; ++mq)
        pf[mq] = *(const short8*)&Pw[wv][(mq * 16 + l15) * 72 + c * 32 + quad * 8];
#pragma unroll
      for (int ntv = 0; ntv < 4; ++ntv) {
        short8 vf = *(const short8*)(vbase + (size_t)(ntv * 16 + l15) * LSEQ +
                                     k0 + c * 32 + quad * 8);
#pragma unroll
        for (int mq = 0; mq < 4; ++mq) O[mq][ntv] = MFMA(pf[mq], vf, O[mq][ntv]);
      }
#pragma unroll
      for (int mq = 0; mq < 4; ++mq) Ol[mq] = MFMA(pf[mq], ones, Ol[mq]);
    }
  }

  // ---- combine the two k-halves through LDS (O,l additive; no max state)
  __syncthreads();
  float* Ored = (float*)&Pw[0][0];  // needs 68*64+64 floats = 17.7 KB <= 18.4
  if (wv == 1) {
#pragma unroll
    for (int ntv = 0; ntv < 4; ++ntv)
#pragma unroll
      for (int mq = 0; mq < 4; ++mq)
        *(f32x4*)&Ored[(ntv * 16 + l15) * 68 + mq * 16 + quad * 4] = O[mq][ntv];
    if (l15 == 0) {
#pragma unroll
      for (int mq = 0; mq < 4; ++mq)
        *(f32x4*)&Ored[68 * 64 + mq * 16 + quad * 4] = Ol[mq];
    }
  }
  __syncthreads();
  if (wv == 0) {
    short* ob = AO + ((size_t)n * LSEQ + q0) * EMB + h * HD;
#pragma unroll
    for (int mq = 0; mq < 4; ++mq) {
      f32x4 lo = *(const f32x4*)&Ored[68 * 64 + mq * 16 + quad * 4];
      f32x4 inv;
#pragma unroll
      for (int r = 0; r < 4; ++r) inv[r] = 1.f / (Ol[mq][r] + lo[r]);
#pragma unroll
      for (int ntv = 0; ntv < 4; ++ntv) {
        f32x4 oo = *(const f32x4*)&Ored[(ntv * 16 + l15) * 68 + mq * 16 + quad * 4];
#pragma unroll
        for (int r = 0; r < 4; ++r)
          ob[(size_t)(mq * 16 + quad * 4 + r) * EMB + ntv * 16 + l15] =
              bf16of((O[mq][ntv][r] + oo[r]) * inv[r]);
      }
    }
  }
}

// ---------------------------------------------------------------------------
// Out-projection: C[r][j] = sum_e A[r][e]*Wo[j][e] + bo[j].
// 128x64 tile/block, grid (16,32)=512 -> 2 blocks/CU. XOR-swizzled LDS,
// double-buffered, register prefetch. (round-4 verified)
__global__ __launch_bounds__(256, 2) void outproj_mfma(
    const short* __restrict__ A, const short* __restrict__ W,
    const float* __restrict__ bo, float* __restrict__ C) {
  __shared__ __align__(16) short As[2][128 * 64];
  __shared__ __align__(16) short Bs[2][64 * 64];
  const int t = threadIdx.x;
  const int wq = t >> 6, lane = t & 63;
  const int quad = lane >> 4, l15 = lane & 15;
  const int j0 = blockIdx.x * 64, r0 = blockIdx.y * 128;

  f32x4 acc[2][4];
#pragma unroll
  for (int a = 0; a < 2; ++a)
#pragma unroll
    for (int b = 0; b < 4; ++b) acc[a][b] = (f32x4){0.f, 0.f, 0.f, 0.f};

  short8 ar[4], br[2];
#pragma unroll
  for (int i = 0; i < 4; ++i) {
    int slot = i * 256 + t, row = slot >> 3, ch = slot & 7;
    ar[i] = *(const short8*)(A + (size_t)(r0 + row) * EMB + ch * 8);
  }
#pragma unroll
  for (int i = 0; i < 2; ++i) {
    int slot = i * 256 + t, row = slot >> 3, ch = slot & 7;
    br[i] = *(const short8*)(W + (size_t)(j0 + row) * EMB + ch * 8);
  }
#pragma unroll
  for (int i = 0; i < 4; ++i) {
    int slot = i * 256 + t, row = slot >> 3, ch = slot & 7;
    *(short8*)&As[0][row * 64 + ((ch ^ (row & 7)) * 8)] = ar[i];
  }
#pragma unroll
  for (int i = 0; i < 2; ++i) {
    int slot = i * 256 + t, row = slot >> 3, ch = slot & 7;
    *(short8*)&Bs[0][row * 64 + ((ch ^ (row & 7)) * 8)] = br[i];
  }
  __syncthreads();

  const int sw0 = ((0 * 4 + quad) ^ (l15 & 7)) * 8;
  const int sw1 = ((1 * 4 + quad) ^ (l15 & 7)) * 8;

  for (int ek = 0; ek < EMB; ek += 64) {
    const int cur = (ek >> 6) & 1, nxt = cur ^ 1;
    if (ek + 64 < EMB) {
#pragma unroll
      for (int i = 0; i < 4; ++i) {
        int slot = i * 256 + t, row = slot >> 3, ch = slot & 7;
        ar[i] = *(const short8*)(A + (size_t)(r0 + row) * EMB + ek + 64 + ch * 8);
      }
#pragma unroll
      for (int i = 0; i < 2; ++i) {
        int slot = i * 256 + t, row = slot >> 3, ch = slot & 7;
        br[i] = *(const short8*)(W + (size_t)(j0 + row) * EMB + ek + 64 + ch * 8);
      }
    }
#pragma unroll
    for (int c = 0; c < 2; ++c) {
      const int sw = c ? sw1 : sw0;
      short8 af[2], bf[4];
#pragma unroll
      for (int mt = 0; mt < 2; ++mt)
        af[mt] = *(const short8*)&As[cur][(wq * 32 + mt * 16 + l15) * 64 + sw];
#pragma unroll
      for (int nt = 0; nt < 4; ++nt)
        bf[nt] = *(const short8*)&Bs[cur][(nt * 16 + l15) * 64 + sw];
#pragma unroll
      for (int mt = 0; mt < 2; ++mt)
#pragma unroll
        for (int nt = 0; nt < 4; ++nt)
          acc[mt][nt] = MFMA(af[mt], bf[nt], acc[mt][nt]);
    }
    if (ek + 64 < EMB) {
#pragma unroll
      for (int i = 0; i < 4; ++i) {
        int slot = i * 256 + t, row = slot >> 3, ch = slot & 7;
        *(short8*)&As[nxt][row * 64 + ((ch ^ (row & 7)) * 8)] = ar[i];
      }
#pragma unroll
      for (int i = 0; i < 2; ++i) {
        int slot = i * 256 + t, row = slot >> 3, ch = slot & 7;
        *(short8*)&Bs[nxt][row * 64 + ((ch ^ (row & 7)) * 8)] = br[i];
      }
    }
    __syncthreads();
  }

  float bn[4];
#pragma unroll
  for (int nt = 0; nt < 4; ++nt) bn[nt] = bo[j0 + nt * 16 + l15];
#pragma unroll
  for (int mt = 0; mt < 2; ++mt)
#pragma unroll
    for (int nt = 0; nt < 4; ++nt)
#pragma unroll
      for (int r = 0; r < 4; ++r)
        C[(size_t)(r0 + wq * 32 + mt * 16 + quad * 4 + r) * EMB + j0 +
          nt * 16 + l15] = acc[mt][nt][r] + bn[nt];
}

// ---------------------------------------------------------------------------
extern "C" void kernel_launch(void* const* d_in, const int* in_sizes, int n_in,
                              void* d_out, int out_size, void* d_ws,
                              size_t ws_size, hipStream_t stream) {
  const float* values = (const float*)d_in[0];
  const float* keys   = (const float*)d_in[1];
  const float* query  = (const float*)d_in[2];
  const int*   mask   = (const int*)d_in[3];
  const float* Wv     = (const float*)d_in[4];
  const float* Wk     = (const float*)d_in[5];
  const float* Wq     = (const float*)d_in[6];
  const float* Wo     = (const float*)d_in[7];
  const float* bo     = (const float*)d_in[8];
  float* out = (float*)d_out;

  short* ws = (short*)d_ws;
  const size_t tsz = (size_t)NB * NHEADS * LSEQ * HD;  // 4 Mi shorts
  short* Qb  = ws;
  short* Kb  = Qb + tsz;
  short* Vt  = Kb + tsz;
  short* AOb = Vt + tsz;
  short* Wob = AOb + tsz;               // 1 Mi shorts
  float* biasf = (float*)(Wob + (size_t)EMB * EMB);  // 4096 floats
  short* Wqb = (short*)(biasf + NB * LSEQ);
  short* Wkb = Wqb + HD * HD;
  short* Wvb = Wkb + HD * HD;

  dim3 blk(256);
  conv_kernel<<<dim3(1024), blk, 0, stream>>>(Wq, Wk, Wv, Wo, mask, Wqb, Wkb,
                                              Wvb, Wob, biasf);
  proj_mfma<<<dim3(LSEQ / 64, NB * NHEADS, 3), blk, 0, stream>>>(
      query, keys, values, Wqb, Wkb, Wvb, Qb, Kb, Vt);
  attn_kernel<<<dim3(LSEQ / 64, NB * NHEADS), dim3(128), 0, stream>>>(
      Qb, Kb, Vt, biasf, AOb);
  outproj_mfma<<<dim3(EMB / 64, NB * LSEQ / 128), blk, 0, stream>>>(AOb, Wob,
                                                                    bo, out);
}